// Round 13
// baseline (68.902 us; speedup 1.0000x reference)
//
#include <hip/hip_runtime.h>

// BiliSample via factorization: bilinear blend and channel-contraction commute.
//   G[b][y][texel][o] = sum_c W[o][c*8+y] * img[b][c][texel]     (bf16, 8 MB)
//   out[o,n] = bias[o] + sum_y sum_corner w_j(n,y) * G[b][y][texel_j][o]
//
//  prep  (384 blocks, proven): imgT[b][texel][c] bf16 c-octet transpose;
//         Wp[o][k'=y*64+c] permuted weights.
//  memset G := 0   (NaN-proofing: any misaddressed read yields 0.0, not junk)
//  gemmG (256 blocks = 2b x 8y x 16chunk): MFMA GEMM -> G columns (o-fastest).
//         Operand/store pattern cloned from the R2-proven kernel (A=W rows via
//         l15, B=imgT cols via l15, same k-octet addressing; D row=lg*4+r,
//         col=l15). launch_bounds(256,1): no forced spill.
//  main  (1250 blocks x 512 thr): phase A -> FULL u32 byte offsets + f32
//         weights in LDS (16 KB); then barrier-free gather-reduce:
//         8y x 4corner x 2 x16B column loads, v_pk_fma_f32. No MFMA, no
//         F-staging. Lane=n -> stores coalesced per o-row.

#define NPOS 40000

typedef short bf16x8 __attribute__((ext_vector_type(8)));
typedef float f32x4  __attribute__((ext_vector_type(4)));

__device__ __forceinline__ unsigned rne16(float f) {
    unsigned u = __float_as_uint(f);
    return (u + 0x7fffu + ((u >> 16) & 1u)) >> 16;
}
__device__ __forceinline__ float lo16(unsigned u) { return __uint_as_float(u << 16); }
__device__ __forceinline__ float hi16(unsigned u) { return __uint_as_float(u & 0xffff0000u); }
__device__ __forceinline__ unsigned cvtpk(float lo, float hi) {
    unsigned r;
    asm("v_cvt_pk_bf16_f32 %0, %1, %2" : "=v"(r) : "v"(lo), "v"(hi));
    return r;
}
// packed f32 fma: a.lo += v.lo*w.lo ; a.hi += v.hi*w.hi  (exact IEEE fma)
__device__ __forceinline__ void pkfma(float2& a, float2 v, float2 w) {
    asm("v_pk_fma_f32 %0, %1, %2, %0" : "+v"(a) : "v"(v), "v"(w));
}

// ---------------- prep: c-octet transpose + W permute (proven) ----------------
__global__ __launch_bounds__(256)
void bili_prep(const float* __restrict__ img, const float* __restrict__ convw,
               unsigned short* __restrict__ imgT, unsigned short* __restrict__ Wp)
{
    const int t = threadIdx.x;
    if (blockIdx.x < 128) {
        // u = ((b*32+y)*64+x)*8 + li8 ; thread packs 8 channels -> one uint4
        const int u   = blockIdx.x * 256 + t;      // 0..32767
        const int li8 = u & 7, x = (u >> 3) & 63, y = (u >> 9) & 31, b = u >> 14;
        const float* src = img + (((b * 64 + li8 * 8) * 32 + y) * 64 + x);
        unsigned pk[4];
        #pragma unroll
        for (int cc = 0; cc < 8; ++cc) {
            const unsigned v = rne16(src[cc * 2048]);
            if ((cc & 1) == 0) pk[cc >> 1] = v;
            else               pk[cc >> 1] |= (v << 16);
        }
        ((uint4*)imgT)[u] = make_uint4(pk[0], pk[1], pk[2], pk[3]);
    } else {
        const int j = (blockIdx.x - 128) * 256 + t;   // 0..65535
        const int k = j & 511, o = j >> 9;
        const int y = k >> 6, c = k & 63;
        Wp[j] = (unsigned short)rne16(convw[o * 512 + c * 8 + y]);
    }
}

// ---------------- gemmG: G[b][y][texel][o] = Wp(y-slice) x imgT^T ----------------
// grid 256 = 2b x 8y x 16 chunks(128 texels). 4 waves; wave = 32 texels x 128 o.
__global__ __launch_bounds__(256, 1)
void bili_gemmG(const unsigned short* __restrict__ imgT,
                const unsigned short* __restrict__ Wp,
                unsigned short* __restrict__ G)
{
    const int t  = threadIdx.x;
    const int bx = blockIdx.x;
    const int ch = bx & 15, y = (bx >> 4) & 7, b = bx >> 7;
    const int wv = t >> 6, ln = t & 63, l15 = ln & 15, lg = ln >> 4;
    const int ts = ch * 128 + wv * 32;

    const bf16x8* Av = (const bf16x8*)Wp;      // [128 o][64 slots]
    const bf16x8* Bv = (const bf16x8*)imgT;    // [b*2048+texel][8 slots]

    // A-fragments: Wp[o = mt*16+l15][y*64 + ks*32 + lg*8 ..+7]
    bf16x8 A[8][2];
    #pragma unroll
    for (int mt = 0; mt < 8; ++mt)
        #pragma unroll
        for (int ks = 0; ks < 2; ++ks)
            A[mt][ks] = Av[(mt * 16 + l15) * 64 + y * 8 + ks * 4 + lg];

    f32x4 acc[8][2];
    #pragma unroll
    for (int mt = 0; mt < 8; ++mt)
        #pragma unroll
        for (int ntt = 0; ntt < 2; ++ntt)
            acc[mt][ntt] = (f32x4){0.0f, 0.0f, 0.0f, 0.0f};

    #pragma unroll
    for (int ks = 0; ks < 2; ++ks) {
        #pragma unroll
        for (int ntt = 0; ntt < 2; ++ntt) {
            const int texel = ts + ntt * 16 + l15;
            const bf16x8 Bf = Bv[(b * 2048 + texel) * 8 + ks * 4 + lg];
            #pragma unroll
            for (int mt = 0; mt < 8; ++mt)
                acc[mt][ntt] = __builtin_amdgcn_mfma_f32_16x16x32_bf16(
                                   A[mt][ks], Bf, acc[mt][ntt], 0, 0, 0);
        }
    }

    // store: D col=l15 -> texel, row=lg*4+r -> o  (proven mapping, o-fastest)
    char* Gb = (char*)G;
    #pragma unroll
    for (int ntt = 0; ntt < 2; ++ntt) {
        const int texel = ts + ntt * 16 + l15;
        const size_t rowoff = (size_t)((b * 8 + y) * 2048 + texel) * 256;  // 128 o x 2B
        #pragma unroll
        for (int mt = 0; mt < 8; ++mt) {
            uint2 pk;
            pk.x = cvtpk(acc[mt][ntt][0], acc[mt][ntt][1]);
            pk.y = cvtpk(acc[mt][ntt][2], acc[mt][ntt][3]);
            *(uint2*)(Gb + rowoff + mt * 32 + lg * 8) = pk;
        }
    }
}

// ---------------- main: barrier-free gather-reduce over G columns ----------------
// grid 1250 x 512 thr (8 waves). lane=n (64-tile), wave wv -> o = wv*16..+15.
__global__ __launch_bounds__(512, 4)
void bili_main(const char* __restrict__ G,       // [b][y][texel][128 o] bf16
               const float* __restrict__ pixT,
               const float* __restrict__ convb,
               float* __restrict__ out)
{
    __shared__ uint4 offs4[8][64];      // [y][nloc]: 4 FULL byte offsets into Gb
    __shared__ float wts4[4][8][64];    // [corner][y][nloc]

    const int t   = threadIdx.x;
    const int bx  = blockIdx.x;
    const int b   = (bx >= 625) ? 1 : 0;
    const int n0  = (bx - b * 625) * 64;

    const int ln  = t & 63;
    const int wv  = t >> 6;             // 0..7

    // ---------- phase A: one projection per thread (proven math) ----------
    {
        const float* Kb = pixT + b * 9;
        const float K00 = Kb[0], K01 = Kb[1], K02 = Kb[2];
        const float K10 = Kb[3], K11 = Kb[4], K12 = Kb[5];
        const float K20 = Kb[6], K21 = Kb[7], K22 = Kb[8];

        const int nloc = t >> 3;
        const int y    = t & 7;
        const int n = n0 + nloc;
        const int z = n / 200;
        const int x = n - z * 200;

        const float pxv = (x * (1.0f / 199.0f) - 0.5f) * 80.0f;
        const float pzv = (z * (1.0f / 199.0f)) * 80.0f;
        const float pyv = (y * (1.0f / 7.0f) - 0.5f) * 6.0f;

        const float p0 = K00 * pxv + K01 * pyv + K02 * pzv;
        const float p1 = K10 * pxv + K11 * pyv + K12 * pzv;
        const float d  = K20 * pxv + K21 * pyv + K22 * pzv;
        const float inv = __builtin_amdgcn_rcpf(d + 1e-8f);
        const float u01 = p0 * inv * (1.0f / 512.0f);
        const float v01 = p1 * inv * (1.0f / 256.0f);
        const float vf = (u01 >= 0.0f && u01 <= 1.0f &&
                          v01 >= 0.0f && v01 <= 1.0f) ? 1.0f : 0.0f;

        float xp = u01 * 64.0f - 0.5f;
        xp = fminf(fmaxf(xp, -2.0f), 66.0f);
        const float x0f = floorf(xp);
        const float wx = xp - x0f;
        const int x0 = (int)x0f, x1i = x0 + 1;
        const float wx0 = (1.0f - wx) * vf * ((x0  >= 0 && x0  < 64) ? 1.0f : 0.0f);
        const float wx1 = wx          * vf * ((x1i >= 0 && x1i < 64) ? 1.0f : 0.0f);
        const int xi0 = min(max(x0, 0), 63);
        const int xi1 = min(max(x1i, 0), 63);

        float yp = v01 * 32.0f - 0.5f;
        yp = fminf(fmaxf(yp, -2.0f), 34.0f);
        const float y0f = floorf(yp);
        const float wy = yp - y0f;
        const int y0 = (int)y0f, y1i = y0 + 1;
        const float wy0 = (1.0f - wy) * ((y0  >= 0 && y0  < 32) ? 1.0f : 0.0f);
        const float wy1 = wy          * ((y1i >= 0 && y1i < 32) ? 1.0f : 0.0f);
        const int yi0 = min(max(y0, 0), 31);
        const int yi1 = min(max(y1i, 0), 31);

        // FULL byte offsets into per-batch G: ((y*2048 + texel) * 256)
        const unsigned yb = (unsigned)(y * 2048);
        const unsigned o0 = (yb + (unsigned)((yi0 << 6) + xi0)) << 8;
        const unsigned o1 = (yb + (unsigned)((yi0 << 6) + xi1)) << 8;
        const unsigned o2 = (yb + (unsigned)((yi1 << 6) + xi0)) << 8;
        const unsigned o3 = (yb + (unsigned)((yi1 << 6) + xi1)) << 8;

        offs4[y][nloc] = make_uint4(o0, o1, o2, o3);
        wts4[0][y][nloc] = wx0 * wy0;
        wts4[1][y][nloc] = wx1 * wy0;
        wts4[2][y][nloc] = wx0 * wy1;
        wts4[3][y][nloc] = wx1 * wy1;
    }

    __syncthreads();

    // ---------- gather-reduce (no barriers, no MFMA) ----------
    const char* Gb = G + (size_t)b * 4194304;     // 8y x 2048 texel x 256B
    const unsigned obyte = (unsigned)(wv * 32);   // this wave's 16-o byte slice

    float2 a0[4], a1[4];                          // o = wv*16 + {0..7}, {8..15}
    {
        const float4 c0 = *(const float4*)(convb + wv * 16);
        const float4 c1 = *(const float4*)(convb + wv * 16 + 4);
        const float4 c2 = *(const float4*)(convb + wv * 16 + 8);
        const float4 c3 = *(const float4*)(convb + wv * 16 + 12);
        a0[0] = make_float2(c0.x, c0.y); a0[1] = make_float2(c0.z, c0.w);
        a0[2] = make_float2(c1.x, c1.y); a0[3] = make_float2(c1.z, c1.w);
        a1[0] = make_float2(c2.x, c2.y); a1[1] = make_float2(c2.z, c2.w);
        a1[2] = make_float2(c3.x, c3.y); a1[3] = make_float2(c3.z, c3.w);
    }

    #pragma unroll
    for (int y = 0; y < 8; ++y) {
        const uint4 oc = offs4[y][ln];
        const float w0 = wts4[0][y][ln];
        const float w1 = wts4[1][y][ln];
        const float w2 = wts4[2][y][ln];
        const float w3 = wts4[3][y][ln];

        #define CORNER(CB, WW)                                                 \
        do {                                                                   \
            const uint4 va = *(const uint4*)(Gb + (CB) + obyte);               \
            const uint4 vb = *(const uint4*)(Gb + (CB) + obyte + 16);          \
            const float2 ww = make_float2(WW, WW);                             \
            float2 t0, t1, t2, t3;                                             \
            t0.x = lo16(va.x); t0.y = hi16(va.x);                              \
            t1.x = lo16(va.y); t1.y = hi16(va.y);                              \
            t2.x = lo16(va.z); t2.y = hi16(va.z);                              \
            t3.x = lo16(va.w); t3.y = hi16(va.w);                              \
            pkfma(a0[0], t0, ww); pkfma(a0[1], t1, ww);                        \
            pkfma(a0[2], t2, ww); pkfma(a0[3], t3, ww);                        \
            t0.x = lo16(vb.x); t0.y = hi16(vb.x);                              \
            t1.x = lo16(vb.y); t1.y = hi16(vb.y);                              \
            t2.x = lo16(vb.z); t2.y = hi16(vb.z);                              \
            t3.x = lo16(vb.w); t3.y = hi16(vb.w);                              \
            pkfma(a1[0], t0, ww); pkfma(a1[1], t1, ww);                        \
            pkfma(a1[2], t2, ww); pkfma(a1[3], t3, ww);                        \
        } while (0)

        CORNER(oc.x, w0);
        CORNER(oc.y, w1);
        CORNER(oc.z, w2);
        CORNER(oc.w, w3);
        #undef CORNER
    }

    // ---------- stores: o-row-major, lanes cover 64 consecutive n ----------
    float* ob = out + (size_t)(b * 128 + wv * 16) * NPOS + n0 + ln;
    #pragma unroll
    for (int j = 0; j < 4; ++j) {
        ob[(2 * j    ) * NPOS] = a0[j].x;
        ob[(2 * j + 1) * NPOS] = a0[j].y;
        ob[(8 + 2 * j    ) * NPOS] = a1[j].x;
        ob[(8 + 2 * j + 1) * NPOS] = a1[j].y;
    }
}

extern "C" void kernel_launch(void* const* d_in, const int* in_sizes, int n_in,
                              void* d_out, int out_size, void* d_ws, size_t ws_size,
                              hipStream_t stream) {
    const float* img   = (const float*)d_in[0];
    const float* pixT  = (const float*)d_in[1];
    const float* convw = (const float*)d_in[2];
    const float* convb = (const float*)d_in[3];
    float* out = (float*)d_out;

    unsigned short* imgT = (unsigned short*)d_ws;                  // 512 KiB
    unsigned short* Wp   = imgT + 262144;                          // 128 KiB
    unsigned short* G    = Wp + 65536;                             // 8 MiB @ byte 655360

    // NaN-proofing: G reads can only see written data or 0.0
    hipMemsetAsync((char*)d_ws + 655360, 0, 8388608, stream);

    hipLaunchKernelGGL(bili_prep, dim3(384), dim3(256), 0, stream,
                       img, convw, imgT, Wp);
    hipLaunchKernelGGL(bili_gemmG, dim3(256), dim3(256), 0, stream,
                       imgT, Wp, G);
    hipLaunchKernelGGL(bili_main, dim3(1250), dim3(512), 0, stream,
                       (const char*)G, pixT, convb, out);
}

// Round 16
// 43.123 us; speedup vs baseline: 1.5978x; 1.5978x over previous
//
#include <hip/hip_runtime.h>

// BiliSample fused: bilinear-sample BEV features + 1x1 conv (GEMM) + bias.
// img_feat (2,64,32,64) f32, pix_T_cam (2,3,3) f32, conv_w (128,512) f32,
// conv_b (128,) f32 -> out (2,128,200,200) f32.
//
//  prep (384 blocks, proven R9): imgT[b][y][x][c] = bf16(img[b][c][y][x])
//        via c-octet transpose (coalesced 16B writes); Wp[o][k'=y*64+c].
//  main (proven R6, 1250 blocks, 64-n tile, 44 KiB LDS, depth-2 pipeline):
//    A: 512 (n,y) projections (rcp fast-path) -> packed offsets + weights LDS
//    8 half-quarters, sbE/sbO alternate (8 uint4 in flight each), F quarters
//    double-buffered; each PROC consumes loads issued earlier with MFMA
//    halves + a barrier in between -> gather latency partially hidden.

#define NPOS 40000

typedef short bf16x8 __attribute__((ext_vector_type(8)));
typedef float f32x4  __attribute__((ext_vector_type(4)));

__device__ __forceinline__ unsigned rne16(float f) {
    unsigned u = __float_as_uint(f);
    return (u + 0x7fffu + ((u >> 16) & 1u)) >> 16;
}
__device__ __forceinline__ float lo16(unsigned u) { return __uint_as_float(u << 16); }
__device__ __forceinline__ float hi16(unsigned u) { return __uint_as_float(u & 0xffff0000u); }
__device__ __forceinline__ unsigned cvtpk(float lo, float hi) {
    unsigned r;
    asm("v_cvt_pk_bf16_f32 %0, %1, %2" : "=v"(r) : "v"(lo), "v"(hi));
    return r;
}

// ---------------- prep: c-octet transpose + W permute (proven R9/R10) ----------------
__global__ __launch_bounds__(256)
void bili_prep(const float* __restrict__ img, const float* __restrict__ convw,
               unsigned short* __restrict__ imgT, unsigned short* __restrict__ Wp)
{
    const int t = threadIdx.x;
    if (blockIdx.x < 128) {
        // u = ((b*32+y)*64+x)*8 + li8 ; thread packs 8 channels -> one uint4
        const int u   = blockIdx.x * 256 + t;      // 0..32767
        const int li8 = u & 7, x = (u >> 3) & 63, y = (u >> 9) & 31, b = u >> 14;
        const float* src = img + (((b * 64 + li8 * 8) * 32 + y) * 64 + x);
        unsigned pk[4];
        #pragma unroll
        for (int cc = 0; cc < 8; ++cc) {
            const unsigned v = rne16(src[cc * 2048]);
            if ((cc & 1) == 0) pk[cc >> 1] = v;
            else               pk[cc >> 1] |= (v << 16);
        }
        ((uint4*)imgT)[u] = make_uint4(pk[0], pk[1], pk[2], pk[3]);
    } else {
        const int j = (blockIdx.x - 128) * 256 + t;   // 0..65535
        const int k = j & 511, o = j >> 9;
        const int y = k >> 6, c = k & 63;
        Wp[j] = (unsigned short)rne16(convw[o * 512 + c * 8 + y]);
    }
}

// ---------------- main fused pipelined kernel (proven R6) ----------------
__global__ __launch_bounds__(256, 3)
void bili_main(const uint4* __restrict__ imgTq,     // per-batch stride 16384 uint4
               const unsigned short* __restrict__ Wp,
               const float* __restrict__ pixT,
               const float* __restrict__ convb,
               float* __restrict__ out)
{
    __shared__ uint4  Fb[2][1024];   // two k-quarter buffers [64 n][16 uint4], swizzled
    __shared__ uint2  offsC[512];    // per (n,y): 4 corner uint4-offsets packed 4 x u16
    __shared__ float4 wtsL[512];     // per (n,y): 4 corner weights (f32)

    const int t   = threadIdx.x;
    const int bx  = blockIdx.x;
    const int b   = (bx >= 625) ? 1 : 0;
    const int n0  = (bx - b * 625) * 64;

    const int wv  = t >> 6;          // wave 0..3 -> o rows wv*32..+31
    const int ln  = t & 63;
    const int l15 = ln & 15;
    const int lg  = ln >> 4;         // k-slot group
    const int g   = t >> 3;          // sample group 0..31
    const int li  = t & 7;           // lane-in-group: channel block

    // ---------- bias preload + acc init ----------
    f32x4 acc0[4], acc1[4];
    {
        float bias0[4], bias1[4];
        #pragma unroll
        for (int r = 0; r < 4; ++r) {
            bias0[r] = convb[wv * 32 +      lg * 4 + r];
            bias1[r] = convb[wv * 32 + 16 + lg * 4 + r];
        }
        #pragma unroll
        for (int nt = 0; nt < 4; ++nt)
            #pragma unroll
            for (int r = 0; r < 4; ++r) { acc0[nt][r] = bias0[r]; acc1[nt][r] = bias1[r]; }
    }

    // ---------- phase A: projections (2 per thread, fast rcp) ----------
    {
        const float* Kb = pixT + b * 9;
        const float K00 = Kb[0], K01 = Kb[1], K02 = Kb[2];
        const float K10 = Kb[3], K11 = Kb[4], K12 = Kb[5];
        const float K20 = Kb[6], K21 = Kb[7], K22 = Kb[8];

        #pragma unroll
        for (int r = 0; r < 2; ++r) {
            const int p    = r * 256 + t;        // 0..511
            const int nloc = p >> 3;
            const int y    = p & 7;
            const int n = n0 + nloc;
            const int z = n / 200;
            const int x = n - z * 200;

            const float pxv = (x * (1.0f / 199.0f) - 0.5f) * 80.0f;
            const float pzv = (z * (1.0f / 199.0f)) * 80.0f;
            const float pyv = (y * (1.0f / 7.0f) - 0.5f) * 6.0f;

            const float p0 = K00 * pxv + K01 * pyv + K02 * pzv;
            const float p1 = K10 * pxv + K11 * pyv + K12 * pzv;
            const float d  = K20 * pxv + K21 * pyv + K22 * pzv;
            const float inv = __builtin_amdgcn_rcpf(d + 1e-8f);
            const float u01 = p0 * inv * (1.0f / 512.0f);
            const float v01 = p1 * inv * (1.0f / 256.0f);
            const float vf = (u01 >= 0.0f && u01 <= 1.0f &&
                              v01 >= 0.0f && v01 <= 1.0f) ? 1.0f : 0.0f;

            float xp = u01 * 64.0f - 0.5f;
            xp = fminf(fmaxf(xp, -2.0f), 66.0f);
            const float x0f = floorf(xp);
            const float wx = xp - x0f;
            const int x0 = (int)x0f, x1i = x0 + 1;
            const float wx0 = (1.0f - wx) * vf * ((x0  >= 0 && x0  < 64) ? 1.0f : 0.0f);
            const float wx1 = wx          * vf * ((x1i >= 0 && x1i < 64) ? 1.0f : 0.0f);
            const int xi0 = min(max(x0, 0), 63);
            const int xi1 = min(max(x1i, 0), 63);

            float yp = v01 * 32.0f - 0.5f;
            yp = fminf(fmaxf(yp, -2.0f), 34.0f);
            const float y0f = floorf(yp);
            const float wy = yp - y0f;
            const int y0 = (int)y0f, y1i = y0 + 1;
            const float wy0 = (1.0f - wy) * ((y0  >= 0 && y0  < 32) ? 1.0f : 0.0f);
            const float wy1 = wy          * ((y1i >= 0 && y1i < 32) ? 1.0f : 0.0f);
            const int yi0 = min(max(y0, 0), 31);
            const int yi1 = min(max(y1i, 0), 31);

            const unsigned o0 = (unsigned)(((yi0 << 6) + xi0) << 3);
            const unsigned o1 = (unsigned)(((yi0 << 6) + xi1) << 3);
            const unsigned o2 = (unsigned)(((yi1 << 6) + xi0) << 3);
            const unsigned o3 = (unsigned)(((yi1 << 6) + xi1) << 3);

            wtsL[p]  = make_float4(wx0 * wy0, wx1 * wy0, wx0 * wy1, wx1 * wy1);
            offsC[p] = make_uint2(o0 | (o1 << 16), o2 | (o3 << 16));
        }
    }

    __syncthreads();

    const uint4*  imgTb = imgTq + b * 16384;
    const bf16x8* ApG   = (const bf16x8*)Wp;           // [128 rows][64 slots]
    const bf16x8* Ap0   = ApG + ((wv * 32 +      l15) * 64 + lg);
    const bf16x8* Ap1   = ApG + ((wv * 32 + 16 + l15) * 64 + lg);

    uint4 sbE[8], sbO[8];

    // issue half-quarter (q, half hb): 8 uint4 loads into SB
    #define ISSUE_H(q, hb, SB)                                                 \
        _Pragma("unroll")                                                      \
        for (int it2 = 0; it2 < 2; ++it2) {                                    \
            const int pp = ((hb) * 2 + it2) * 32 + g;                          \
            const int n_ = pp >> 1, ys = pp & 1;                               \
            const int p_ = n_ * 8 + 2 * (q) + ys;                              \
            const uint2 oc = offsC[p_];                                        \
            SB[it2 * 4 + 0] = imgTb[(oc.x & 0xffffu) + li];                    \
            SB[it2 * 4 + 1] = imgTb[(oc.x >> 16)     + li];                    \
            SB[it2 * 4 + 2] = imgTb[(oc.y & 0xffffu) + li];                    \
            SB[it2 * 4 + 3] = imgTb[(oc.y >> 16)     + li];                    \
        }

    // bilinear-combine half-quarter, pack bf16, write F buffer
    #define PROC_H(q, hb, SB, buf)                                             \
        _Pragma("unroll")                                                      \
        for (int it2 = 0; it2 < 2; ++it2) {                                    \
            const int pp = ((hb) * 2 + it2) * 32 + g;                          \
            const int n_ = pp >> 1, ys = pp & 1;                               \
            const int p_ = n_ * 8 + 2 * (q) + ys;                              \
            const float4 w = wtsL[p_];                                         \
            float2 ac[4];                                                      \
            _Pragma("unroll")                                                  \
            for (int qq = 0; qq < 4; ++qq) ac[qq] = make_float2(0.0f, 0.0f);   \
            _Pragma("unroll")                                                  \
            for (int j = 0; j < 4; ++j) {                                      \
                const uint4 v = SB[it2 * 4 + j];                               \
                const float ww = (j == 0) ? w.x : (j == 1) ? w.y : (j == 2) ? w.z : w.w; \
                ac[0].x = fmaf(ww, lo16(v.x), ac[0].x);                        \
                ac[0].y = fmaf(ww, hi16(v.x), ac[0].y);                        \
                ac[1].x = fmaf(ww, lo16(v.y), ac[1].x);                        \
                ac[1].y = fmaf(ww, hi16(v.y), ac[1].y);                        \
                ac[2].x = fmaf(ww, lo16(v.z), ac[2].x);                        \
                ac[2].y = fmaf(ww, hi16(v.z), ac[2].y);                        \
                ac[3].x = fmaf(ww, lo16(v.w), ac[3].x);                        \
                ac[3].y = fmaf(ww, hi16(v.w), ac[3].y);                        \
            }                                                                  \
            uint4 pk;                                                          \
            pk.x = cvtpk(ac[0].x, ac[0].y);                                    \
            pk.y = cvtpk(ac[1].x, ac[1].y);                                    \
            pk.z = cvtpk(ac[2].x, ac[2].y);                                    \
            pk.w = cvtpk(ac[3].x, ac[3].y);                                    \
            (buf)[n_ * 16 + ((ys * 8 + li) ^ (n_ & 7))] = pk;                  \
        }

    // MFMA half (k pair) of quarter q out of buf; W loads L1/L2-hot
    #define MFMA_H(q, hf, buf)                                                 \
        do {                                                                   \
            const bf16x8* Fv = (const bf16x8*)(buf);                           \
            _Pragma("unroll")                                                  \
            for (int k2 = 0; k2 < 2; ++k2) {                                   \
                const int k = (hf) * 2 + k2;                                   \
                const bf16x8 a0_ = Ap0[((q) * 4 + k) * 4];                     \
                const bf16x8 a1_ = Ap1[((q) * 4 + k) * 4];                     \
                _Pragma("unroll")                                              \
                for (int nt = 0; nt < 4; ++nt) {                               \
                    const int nn = nt * 16 + l15;                              \
                    const bf16x8 bv = Fv[nn * 16 + ((k * 4 + lg) ^ (nn & 7))]; \
                    acc0[nt] = __builtin_amdgcn_mfma_f32_16x16x32_bf16(a0_, bv, acc0[nt], 0, 0, 0); \
                    acc1[nt] = __builtin_amdgcn_mfma_f32_16x16x32_bf16(a1_, bv, acc1[nt], 0, 0, 0); \
                }                                                              \
            }                                                                  \
        } while (0)

    // ---------- depth-2 half-quarter pipeline ----------
    ISSUE_H(0, 0, sbE);
    ISSUE_H(0, 1, sbO);
    PROC_H (0, 0, sbE, Fb[0]);
    ISSUE_H(1, 0, sbE);
    PROC_H (0, 1, sbO, Fb[0]);
    __syncthreads();

    ISSUE_H(1, 1, sbO);
    MFMA_H (0, 0, Fb[0]);
    PROC_H (1, 0, sbE, Fb[1]);
    ISSUE_H(2, 0, sbE);
    MFMA_H (0, 1, Fb[0]);
    PROC_H (1, 1, sbO, Fb[1]);
    __syncthreads();

    ISSUE_H(2, 1, sbO);
    MFMA_H (1, 0, Fb[1]);
    PROC_H (2, 0, sbE, Fb[0]);
    ISSUE_H(3, 0, sbE);
    MFMA_H (1, 1, Fb[1]);
    PROC_H (2, 1, sbO, Fb[0]);
    __syncthreads();

    ISSUE_H(3, 1, sbO);
    MFMA_H (2, 0, Fb[0]);
    PROC_H (3, 0, sbE, Fb[1]);
    MFMA_H (2, 1, Fb[0]);
    PROC_H (3, 1, sbO, Fb[1]);
    __syncthreads();

    MFMA_H (3, 0, Fb[1]);
    MFMA_H (3, 1, Fb[1]);

    #undef ISSUE_H
    #undef PROC_H
    #undef MFMA_H

    // ---------- stores ----------
    {
        float* ob = out + (size_t)(b * 128 + wv * 32) * NPOS + n0;
        #pragma unroll
        for (int nt = 0; nt < 4; ++nt) {
            #pragma unroll
            for (int r = 0; r < 4; ++r) {
                ob[(     lg * 4 + r) * NPOS + nt * 16 + l15] = acc0[nt][r];
                ob[(16 + lg * 4 + r) * NPOS + nt * 16 + l15] = acc1[nt][r];
            }
        }
    }
}

extern "C" void kernel_launch(void* const* d_in, const int* in_sizes, int n_in,
                              void* d_out, int out_size, void* d_ws, size_t ws_size,
                              hipStream_t stream) {
    const float* img   = (const float*)d_in[0];
    const float* pixT  = (const float*)d_in[1];
    const float* convw = (const float*)d_in[2];
    const float* convb = (const float*)d_in[3];
    float* out = (float*)d_out;

    unsigned short* imgT = (unsigned short*)d_ws;             // 262144 bf16 = 512 KiB
    unsigned short* Wp   = imgT + 262144;                     // 65536 bf16 = 128 KiB

    hipLaunchKernelGGL(bili_prep, dim3(384), dim3(256), 0, stream,
                       img, convw, imgT, Wp);
    hipLaunchKernelGGL(bili_main, dim3(1250), dim3(256), 0, stream,
                       (const uint4*)imgT, Wp, pixT, convb, out);
}